// Round 9
// baseline (2746.768 us; speedup 1.0000x reference)
//
#include <hip/hip_runtime.h>
#include <stdint.h>

// Problem constants
#define B_   128
#define C_   512
#define P_   196
#define PP_  200     // padded P for bf16 image features rows
#define T_   32
#define V_   10403
#define E_   128
#define U_   256
#define KX_  896     // C+E+U : X row width in PAIRED u32 units (attn|emb|h)
#define K2_  1792    // doubled K for hi/lo split GEMM
#define NPAD_ 10496  // 82 * 128, padded N for the logits GEMM
#define WLD_ 904     // padded LDS row stride (bf16 elems) for gates tiles
#define NBLK_ 128    // fused-loop grid (1 block/CU by LDS; all co-resident)

typedef unsigned short u16;
typedef __attribute__((ext_vector_type(8))) short bf16x8;
typedef __attribute__((ext_vector_type(4))) float f32x4;

__device__ __forceinline__ float b2f(u16 u){
  union { unsigned int i; float f; } v; v.i = ((unsigned int)u) << 16; return v.f;
}
__device__ __forceinline__ u16 f2b(float f){
  union { float f; unsigned int i; } v; v.f = f;
  unsigned int r = (v.i + 0x7FFFu + ((v.i >> 16) & 1u)) >> 16;
  return (u16)r;
}
// duplicate one bf16 value into both halves of a u32 (K-doubled X element)
__device__ __forceinline__ unsigned int dup(float a){
  return (unsigned int)f2b(a) * 0x00010001u;
}
// hi/lo split of fp32 weight into two bf16 halves packed in one u32
__device__ __forceinline__ unsigned int hl(float w){
  u16 h = f2b(w);
  float lo = w - b2f(h);
  return (unsigned int)h | ((unsigned int)f2b(lo) << 16);
}

// ------------- prep: mean over P + bf16 image features [b][c][200] -----
__global__ void k_prep(const float* __restrict__ imf, float* __restrict__ mean,
                       u16* __restrict__ imb){
  int idx = blockIdx.x * 256 + threadIdx.x;          // b*C + c, 65536 total
  const float4* p4 = (const float4*)(imf + (size_t)idx * P_);
  u16* orow = imb + (size_t)idx * PP_;
  float s = 0.f;
  for (int i = 0; i < 49; ++i){
    float4 q = p4[i];
    s += q.x + q.y + q.z + q.w;
    ushort4 o;
    o.x = f2b(q.x); o.y = f2b(q.y); o.z = f2b(q.z); o.w = f2b(q.w);
    *((ushort4*)(orow + 4 * i)) = o;
  }
  ushort4 z; z.x = z.y = z.z = z.w = 0;
  *((ushort4*)(orow + 196)) = z;
  mean[idx] = s * (1.f / 196.f);
}

// ------- h0 = mean@W_h0^T + b_h0 ; c0 = mean@W_c0^T + b_c0 (+dup h0) ---
__global__ void k_h0c0(const float* __restrict__ mean,
                       const float* __restrict__ Wh, const float* __restrict__ bh,
                       const float* __restrict__ Wc, const float* __restrict__ bc,
                       float* __restrict__ h0, float* __restrict__ c0,
                       unsigned int* __restrict__ h0b){
  int idx = blockIdx.x * 256 + threadIdx.x;          // b*512 + j
  int b = idx >> 9, j = idx & 511;
  int u = j & 255, isc = j >> 8;
  const float* wr = (isc ? Wc : Wh) + (size_t)u * C_;
  const float* m = mean + b * C_;
  float s = 0.f;
  for (int c = 0; c < C_; ++c) s += m[c] * wr[c];
  s += (isc ? bc : bh)[u];
  (isc ? c0 : h0)[b * U_ + u] = s;
  if (!isc) h0b[b * U_ + u] = dup(s);
}

// ---------------- Wkey f32 -> bf16 -----------------------------------
__global__ void k_wkeyb(const float* __restrict__ Wk, u16* __restrict__ WkB){
  int idx = blockIdx.x * 256 + threadIdx.x;          // 256*512 = 131072
  WkB[idx] = f2b(Wk[idx]);
}

// ------- gate weights -> bf16, columns reordered to attn|emb|h ---------
__global__ void k_wgb(const float* __restrict__ Wih, const float* __restrict__ Whh,
                      u16* __restrict__ Wg){
  int idx = blockIdx.x * 256 + threadIdx.x;          // 1024*896
  int j = idx / 896, k = idx - j * 896;
  float w;
  if (k < 512)      w = Wih[(size_t)j * 640 + 128 + k];   // attn part
  else if (k < 640) w = Wih[(size_t)j * 640 + (k - 512)]; // emb part
  else              w = Whh[(size_t)j * 256 + (k - 640)]; // h part
  Wg[(size_t)j * 896 + k] = f2b(w);
}

// --------- X emb columns for all (b,t) + zero the loop barrier ---------
__global__ void k_xemb(const int* __restrict__ cap, const float* __restrict__ emb,
                       unsigned int* __restrict__ X, unsigned int* __restrict__ bar){
  int idx = blockIdx.x * 256 + threadIdx.x;          // row*128 + e, 4096*128
  if (idx == 0) *bar = 0u;                           // re-zero each launch/replay
  int row = idx >> 7, e = idx & 127;
  int ix = cap[row];                                 // row = b*T + t
  X[(size_t)row * KX_ + C_ + e] = dup(emb[(size_t)ix * E_ + e]);
}

// ---------------- keysT[b,p,u] = sum_c Wkey[u,c] * imf[b,c,p] ----------
// one-time MFMA GEMM, bf16 out, u-contiguous rows. grid (13 p-tiles x 128 b).
__global__ void __launch_bounds__(256) k_keys(
    const float* __restrict__ imf, const u16* __restrict__ WkeyB,
    u16* __restrict__ keysT)
{
  __shared__ __align__(16) u16 Bs[16 * 40];   // [p][k], stride 40 breaks conflicts
  int tid = threadIdx.x;
  int p0 = blockIdx.x * 16;                   // 0..192
  int b  = blockIdx.y;
  int lane = tid & 63, wv = tid >> 6;
  int quad = lane >> 4, l15 = lane & 15;
  f32x4 acc[4];
  #pragma unroll
  for (int m = 0; m < 4; ++m) acc[m] = (f32x4){0.f, 0.f, 0.f, 0.f};
  for (int kc = 0; kc < 16; ++kc){
    int k0 = kc * 32;
    #pragma unroll
    for (int e = tid; e < 512; e += 256){
      int kk = e >> 4, pp = e & 15;
      int p = p0 + pp;
      float v = (p < P_) ? imf[((size_t)b * C_ + (k0 + kk)) * P_ + p] : 0.f;
      Bs[pp * 40 + kk] = f2b(v);
    }
    __syncthreads();
    bf16x8 bfrag = *((const bf16x8*)(Bs + l15 * 40 + quad * 8));
    #pragma unroll
    for (int m = 0; m < 4; ++m){
      int u = wv * 64 + m * 16 + l15;
      bf16x8 afrag = *((const bf16x8*)(WkeyB + (size_t)u * C_ + k0 + quad * 8));
      acc[m] = __builtin_amdgcn_mfma_f32_16x16x32_bf16(afrag, bfrag, acc[m], 0, 0, 0);
    }
    __syncthreads();
  }
  int p = p0 + l15;
  if (p < P_){
    #pragma unroll
    for (int m = 0; m < 4; ++m){
      ushort4 o;
      o.x = f2b(acc[m][0]); o.y = f2b(acc[m][1]);
      o.z = f2b(acc[m][2]); o.w = f2b(acc[m][3]);
      *((ushort4*)(keysT + ((size_t)b * P_ + p) * U_ + wv * 64 + m * 16 + quad * 4)) = o;
    }
  }
}

// ===== fused recurrent loop: 1 dispatch, software grid barrier =========
// Plain (graph-capturable) launch. 128 blocks x 256 thr, ~152 KB LDS
// -> hard 1 block/CU, 128 < 256 CUs => all blocks co-resident.
// Barrier: monotonic device-scope atomic counter + spin (m20: atomics are
// cross-XCD coherent); __threadfence release before / acquire after.
// attn phase: block = one b (round-4 body, both c-halves).
// gates phase: block = (b-tile, u-tile) (round-8 gates3 body); W-tile
// staged into LDS ONCE for all 32 steps.
__global__ void __launch_bounds__(256) k_loopf(
    const u16* __restrict__ imb, const u16* __restrict__ keysT,
    const u16* __restrict__ Wg, const float* __restrict__ bih,
    const float* __restrict__ bhh, const unsigned int* __restrict__ h0b,
    float* __restrict__ c_st, float* __restrict__ hbuf0,
    float* __restrict__ hbuf1, unsigned int* X, float* __restrict__ maps,
    unsigned int* bar)
{
  __shared__ __align__(16) u16 wls[64 * WLD_];   // 115,712 B (persistent W)
  __shared__ __align__(16) u16 xls[16 * WLD_];   //  28,928 B
  __shared__ __align__(16) float gl[4 * 16 * 16];
  __shared__ __align__(16) float qs[256];
  __shared__ __align__(16) float red[256];
  __shared__ __align__(16) float wl[256];
  int blk = blockIdx.x, tid = threadIdx.x;
  int b0 = (blk >> 4) * 16;                   // gates tile
  int u0 = (blk & 15) * 16;
  int lane = tid & 63, wv = tid >> 6;
  int quad = lane >> 4, l15 = lane & 15;

  // ---- stage W tile ONCE: 64 rows (4 gates x 16 u) x 112 8-elem chunks
  for (int e = tid; e < 64 * 112; e += 256){
    int jl = e / 112, s8 = e - jl * 112;
    int j = ((jl >> 4) << 8) + u0 + (jl & 15);
    uint4 v = *((const uint4*)(Wg + (size_t)j * 896 + s8 * 8));
    *((uint4*)(wls + jl * WLD_ + s8 * 8)) = v;
  }

  unsigned int btgt = 0;
  for (int t = 0; t < T_; ++t){
    const float* qsrc = (t == 0) ? c_st : ((t & 1) ? hbuf1 : hbuf0);
    float*       hn   = (t & 1) ? hbuf0 : hbuf1;

    // ---------------- attention phase: b = blk ------------------------
    {
      int b = blk;
      qs[tid] = qsrc[b * U_ + tid];
      __syncthreads();
      float s = -1e30f;
      if (tid < P_){
        const u16* kp = keysT + ((size_t)b * P_ + tid) * U_;
        float acc = 0.f;
        #pragma unroll
        for (int i = 0; i < 32; ++i){
          bf16x8 v8 = *((const bf16x8*)(kp + i * 8));
          #pragma unroll
          for (int j = 0; j < 8; ++j) acc += qs[i * 8 + j] * b2f((u16)v8[j]);
        }
        s = acc * 0.0625f;   // 1/sqrt(256)
      }
      red[tid] = s; __syncthreads();
      for (int off = 128; off > 0; off >>= 1){
        if (tid < off) red[tid] = fmaxf(red[tid], red[tid + off]);
        __syncthreads();
      }
      float mx = red[0]; __syncthreads();
      float e = (tid < P_) ? __expf(s - mx) : 0.f;
      red[tid] = e; __syncthreads();
      for (int off = 128; off > 0; off >>= 1){
        if (tid < off) red[tid] += red[tid + off];
        __syncthreads();
      }
      float inv = 1.f / red[0];
      float w = e * inv;                       // 0 for tid >= P_
      wl[tid] = w;
      if (tid < P_)
        maps[(size_t)(b * T_ + t) * P_ + tid] = w;
      __syncthreads();
      size_t xrow = (size_t)(b * T_ + t) * KX_;
      #pragma unroll
      for (int cc = 0; cc < 2; ++cc){
        int c = cc * 256 + tid;
        const u16* vrow = imb + ((size_t)b * C_ + c) * PP_;
        float a = 0.f;
        #pragma unroll
        for (int i = 0; i < 25; ++i){
          bf16x8 v8 = *((const bf16x8*)(vrow + i * 8));
          #pragma unroll
          for (int j = 0; j < 8; ++j) a += wl[i * 8 + j] * b2f((u16)v8[j]);
        }
        X[xrow + c] = dup(a);
      }
    }
    // ---- grid barrier (attn -> gates) --------------------------------
    __threadfence();                            // release
    __syncthreads();
    btgt += NBLK_;
    if (tid == 0){
      __hip_atomic_fetch_add(bar, 1u, __ATOMIC_ACQ_REL, __HIP_MEMORY_SCOPE_AGENT);
      while (__hip_atomic_load(bar, __ATOMIC_ACQUIRE, __HIP_MEMORY_SCOPE_AGENT) < btgt)
        __builtin_amdgcn_s_sleep(2);
    }
    __syncthreads();
    __threadfence();                            // acquire

    // ---------------- gates phase (round-8 gates3 body) ---------------
    {
      // stage X-rows tile: 16 rows x 224 u32-quads (dup -> low bf16)
      for (int e = tid; e < 16 * 224; e += 256){
        int r = e / 224, q4 = e - r * 224;
        const unsigned int* src;
        if (q4 < 160)       src = X + ((size_t)((b0 + r) * T_ + t)) * KX_ + q4 * 4;
        else if (t > 0)     src = X + ((size_t)((b0 + r) * T_ + t - 1)) * KX_ + q4 * 4;
        else                src = h0b + (b0 + r) * U_ + (q4 * 4 - 640);
        uint4 v = *((const uint4*)src);
        ushort4 o;
        o.x = (u16)v.x; o.y = (u16)v.y; o.z = (u16)v.z; o.w = (u16)v.w;
        *((ushort4*)(xls + r * WLD_ + q4 * 4)) = o;
      }
      __syncthreads();
      f32x4 acc = {0.f, 0.f, 0.f, 0.f};
      #pragma unroll
      for (int kc = 0; kc < 28; ++kc){
        bf16x8 af  = *((const bf16x8*)(xls + l15 * WLD_ + kc * 32 + quad * 8));
        bf16x8 bfv = *((const bf16x8*)(wls + (wv * 16 + l15) * WLD_ + kc * 32 + quad * 8));
        acc = __builtin_amdgcn_mfma_f32_16x16x32_bf16(af, bfv, acc, 0, 0, 0);
      }
      #pragma unroll
      for (int r = 0; r < 4; ++r)
        gl[(wv << 8) + ((quad * 4 + r) << 4) + l15] = acc[r];
      __syncthreads();
      {
        int br = tid >> 4, ur = tid & 15;
        int b = b0 + br, u = u0 + ur;
        float i_g = gl[(0 << 8) + (br << 4) + ur] + bih[u]       + bhh[u];
        float f_g = gl[(1 << 8) + (br << 4) + ur] + bih[256 + u] + bhh[256 + u];
        float g_g = gl[(2 << 8) + (br << 4) + ur] + bih[512 + u] + bhh[512 + u];
        float o_g = gl[(3 << 8) + (br << 4) + ur] + bih[768 + u] + bhh[768 + u];
        float cold = c_st[b * U_ + u];
        float si = 1.f / (1.f + __expf(-i_g));
        float sf = 1.f / (1.f + __expf(-f_g));
        float so = 1.f / (1.f + __expf(-o_g));
        float cn = sf * cold + si * tanhf(g_g);
        float hnv = so * tanhf(cn);
        c_st[b * U_ + u] = cn;
        hn[b * U_ + u] = hnv;
        X[(size_t)(b * T_ + t) * KX_ + 640 + u] = dup(hnv);
      }
    }
    // ---- grid barrier (gates -> next attn) ---------------------------
    __threadfence();                            // release
    __syncthreads();
    btgt += NBLK_;
    if (tid == 0){
      __hip_atomic_fetch_add(bar, 1u, __ATOMIC_ACQ_REL, __HIP_MEMORY_SCOPE_AGENT);
      while (__hip_atomic_load(bar, __ATOMIC_ACQUIRE, __HIP_MEMORY_SCOPE_AGENT) < btgt)
        __builtin_amdgcn_s_sleep(2);
    }
    __syncthreads();
    __threadfence();                            // acquire
  }
}

// ---------------- W_out -> hi/lo bf16 pairs, zero-padded to NPAD_ ------
__global__ void k_wsplit(const float* __restrict__ Wout,
                         unsigned int* __restrict__ W2){
  int idx = blockIdx.x * 256 + threadIdx.x;        // NPAD_*224 = 2,351,104
  int v = idx / 224, kq = idx - v * 224;
  uint4 o;
  if (v < V_){
    float4 w = ((const float4*)(Wout + (size_t)v * KX_))[kq];
    o.x = hl(w.x); o.y = hl(w.y); o.z = hl(w.z); o.w = hl(w.w);
  } else {
    o.x = o.y = o.z = o.w = 0u;
  }
  ((uint4*)(W2 + (size_t)v * KX_))[kq] = o;
}

// ---------------- logits GEMM: MFMA, m97 structure ---------------------
// C[4096, NPAD_] = A2[4096, K2_] * W2[NPAD_, K2_]^T  (bf16, K doubled)
__global__ void __launch_bounds__(256) k_logits(
    const u16* __restrict__ A2, const u16* __restrict__ W2,
    const float* __restrict__ bout, float* __restrict__ out)
{
  __shared__ __align__(16) u16 As[128 * 32];
  __shared__ __align__(16) u16 Bs[128 * 32];
  int tid = threadIdx.x;
  int n0 = blockIdx.x * 128;
  int m0 = blockIdx.y * 128;
  int lane = tid & 63, wv = tid >> 6;
  int wm = wv >> 1, wn = wv & 1;
  int quad = lane >> 4, l15 = lane & 15;

  f32x4 acc[4][4];
  #pragma unroll
  for (int i = 0; i < 4; ++i)
    #pragma unroll
    for (int j = 0; j < 4; ++j)
      acc[i][j] = (f32x4){0.f, 0.f, 0.f, 0.f};

  int rsub = tid >> 2, seg = tid & 3;
  const u16* ga0 = A2 + (size_t)(m0 + rsub)      * K2_ + seg * 8;
  const u16* ga1 = A2 + (size_t)(m0 + 64 + rsub) * K2_ + seg * 8;
  const u16* gb0 = W2 + (size_t)(n0 + rsub)      * K2_ + seg * 8;
  const u16* gb1 = W2 + (size_t)(n0 + 64 + rsub) * K2_ + seg * 8;
  u16* lA0 = As + tid * 8;
  u16* lA1 = As + (256 + tid) * 8;
  u16* lB0 = Bs + tid * 8;
  u16* lB1 = Bs + (256 + tid) * 8;

  const u16* arow0 = As + (wm * 64 + l15) * 32 + quad * 8;
  const u16* brow0 = Bs + (wn * 64 + l15) * 32 + quad * 8;

  for (int kc = 0; kc < 56; ++kc){
    __builtin_amdgcn_global_load_lds(ga0, lA0, 16, 0, 0);
    __builtin_amdgcn_global_load_lds(ga1, lA1, 16, 0, 0);
    __builtin_amdgcn_global_load_lds(gb0, lB0, 16, 0, 0);
    __builtin_amdgcn_global_load_lds(gb1, lB1, 16, 0, 0);
    ga0 += 32; ga1 += 32; gb0 += 32; gb1 += 32;
    __syncthreads();
    bf16x8 a[4], b[4];
    #pragma unroll
    for (int i = 0; i < 4; ++i)
      a[i] = *((const bf16x8*)(arow0 + i * 16 * 32));
    #pragma unroll
    for (int j = 0; j < 4; ++j)
      b[j] = *((const bf16x8*)(brow0 + j * 16 * 32));
    #pragma unroll
    for (int i = 0; i < 4; ++i)
      #pragma unroll
      for (int j = 0; j < 4; ++j)
        acc[i][j] = __builtin_amdgcn_mfma_f32_16x16x32_bf16(a[i], b[j], acc[i][j], 0, 0, 0);
    __syncthreads();
  }

  int orow = m0 + wm * 64 + quad * 4;
  #pragma unroll
  for (int j = 0; j < 4; ++j){
    int v = n0 + wn * 64 + j * 16 + l15;
    if (v < V_){
      float bo = bout[v];
      #pragma unroll
      for (int i = 0; i < 4; ++i){
        #pragma unroll
        for (int r = 0; r < 4; ++r)
          out[(size_t)(orow + i * 16 + r) * V_ + v] = acc[i][j][r] + bo;
      }
    }
  }
}

extern "C" void kernel_launch(void* const* d_in, const int* in_sizes, int n_in,
                              void* d_out, int out_size, void* d_ws, size_t ws_size,
                              hipStream_t stream)
{
  const float* imf  = (const float*)d_in[0];
  const int*   cap  = (const int*)d_in[1];
  const float* Wh0  = (const float*)d_in[2];
  const float* bh0  = (const float*)d_in[3];
  const float* Wc0  = (const float*)d_in[4];
  const float* bc0  = (const float*)d_in[5];
  const float* Wkey = (const float*)d_in[6];
  // d_in[7] = b_key: softmax-invariant (constant shift per b) -> unused
  const float* emb  = (const float*)d_in[8];
  const float* Wih  = (const float*)d_in[9];
  const float* bih  = (const float*)d_in[10];
  const float* Whh  = (const float*)d_in[11];
  const float* bhh  = (const float*)d_in[12];
  const float* Wout = (const float*)d_in[13];
  const float* bout = (const float*)d_in[14];

  // workspace layout (~94 MB)
  float* mean  = (float*)d_ws;                        // 65536 f32
  float* hbuf0 = mean  + 65536;                       // 32768
  float* hbuf1 = hbuf0 + 32768;                       // 32768
  float* cbuf  = hbuf1 + 32768;                       // 32768
  unsigned int* h0b = (unsigned int*)(cbuf + 32768);  // 32768 u32 (dup h0)
  unsigned int* bar = h0b + 32768;                    // 256 u32 (barrier)
  unsigned int* X   = bar + 256;                      // 4096*896 u32 (dup bf16)
  unsigned int* W2  = X + (size_t)4096 * KX_;         // 10496*896 u32 (hi|lo)
  u16* Wg    = (u16*)(W2 + (size_t)NPAD_ * KX_);      // 1024*896 bf16 (reordered)
  u16* WkeyB = Wg + (size_t)1024 * 896;               // 256*512 bf16
  u16* keysT = WkeyB + 131072;                        // 128*196*256 bf16 [b][p][u]
  u16* imb   = keysT + (size_t)B_ * P_ * U_;          // 128*512*200 bf16

  float* out  = (float*)d_out;
  float* maps = out + (size_t)B_ * T_ * V_;

  k_wsplit<<<9184, 256, 0, stream>>>(Wout, W2);
  k_wgb<<<3584, 256, 0, stream>>>(Wih, Whh, Wg);
  k_wkeyb<<<512, 256, 0, stream>>>(Wkey, WkeyB);
  k_prep<<<256, 256, 0, stream>>>(imf, mean, imb);
  k_keys<<<dim3(13, 128), 256, 0, stream>>>(imf, WkeyB, keysT);
  k_h0c0<<<256, 256, 0, stream>>>(mean, Wh0, bh0, Wc0, bc0, hbuf0, cbuf, h0b);
  k_xemb<<<2048, 256, 0, stream>>>(cap, emb, X, bar);

  k_loopf<<<NBLK_, 256, 0, stream>>>((const u16*)imb, keysT, Wg, bih, bhh,
                                     h0b, cbuf, hbuf0, hbuf1, X, maps, bar);

  k_logits<<<dim3(82, 32), 256, 0, stream>>>((const u16*)X, (const u16*)W2,
                                             bout, out);
}